// Round 6
// baseline (207.863 us; speedup 1.0000x reference)
//
#include <hip/hip_runtime.h>
#include <cstdint>
#include <cstddef>

// Problem constants
#define R_DIM   128
#define R2_DIM  64
#define MIX     32
#define IN_DIM  512
#define HID     256
#define B_SZ    256
#define T_SZ    16
#define MAX_IT  12

// Workspace layout (float offsets)
#define OFF_G    0           // 16384 floats (row-major 128x128, pre-folded M = 0.8I - 0.2G)
#define OFF_U    24576       // 4096*128
#define OFF_SX   548864      // 4096
#define OFF_FLAG 552960      // 1 int: 1 = absorbing fast mode (hypernet(0) == 0)
#define OFF_LOSS 552961      // 48 floats: [3][16] per-t loss partials (fast mode)

__device__ __forceinline__ float softt(float v, float lam) {
  float a = fabsf(v) - lam;
  return a > 0.f ? (v > 0.f ? a : -a) : 0.f;
}

__device__ __forceinline__ float rdlane(float v, int lane) {
  int i = __builtin_amdgcn_readlane(__float_as_int(v), lane);
  return __int_as_float(i);
}

__device__ __forceinline__ float wsum_all(float v) {  // within wave64
#pragma unroll
  for (int off = 32; off; off >>= 1) v += __shfl_xor(v, off, 64);
  return v;
}

__device__ __forceinline__ float wsum(float v) {  // lane 0 of each wave
#pragma unroll
  for (int off = 32; off; off >>= 1) v += __shfl_down(v, off, 64);
  return v;
}

// Sum of the two kh-half partials held by lanes l and l+32 (a=b form validated
// green in R3/R5 benches). Pure VALU, no LDS round-trip.
__device__ __forceinline__ float pairsum32(float pm) {
  float a = pm, b = pm;
  asm volatile("v_permlane32_swap_b32 %0, %1" : "+v"(a), "+v"(b));
  return a + b;
}

// =============== COLD hypernet path: __noinline__, 64-lane (wave 0 only) ======
__device__ void ensure_c_dev(int l, const float* __restrict__ T2, float* cS,
                             int* cstL, const float* rpL) {
  if (cstL[0]) return;  // wave-0-only caller: uniform
  for (int p = l; p < MIX * R_DIM; p += 64) {
    const float* row = T2 + (size_t)p * R_DIM;
    float acc = 0.f;
    for (int j4 = 0; j4 < R_DIM / 4; j4++) {
      float4 w4 = *(const float4*)(row + j4 * 4);
      float4 r4 = *(const float4*)(rpL + j4 * 4);
      acc += w4.x * r4.x + w4.y * r4.y + w4.z * r4.z + w4.w * r4.w;
    }
    cS[(p >> 7) * 129 + (p & 127)] = acc;
  }
  if (l == 0) cstL[0] = 1;
}

__device__ __noinline__ float2 rhat_cold(int l, const float* __restrict__ T2,
                                         float* cS, int* cstL,
                                         const float* rpL, const float* wL) {
  ensure_c_dev(l, T2, cS, cstL, rpL);
  float a0 = 0.f, a1 = 0.f;
#pragma unroll
  for (int m4 = 0; m4 < 8; m4++) {
    float4 w4 = *(const float4*)&wL[m4 * 4];
    int mb = m4 * 4;
    a0 += w4.x * cS[(mb + 0) * 129 + l] + w4.y * cS[(mb + 1) * 129 + l] +
          w4.z * cS[(mb + 2) * 129 + l] + w4.w * cS[(mb + 3) * 129 + l];
    a1 += w4.x * cS[(mb + 0) * 129 + 64 + l] + w4.y * cS[(mb + 1) * 129 + 64 + l] +
          w4.z * cS[(mb + 2) * 129 + 64 + l] + w4.w * cS[(mb + 3) * 129 + 64 + l];
  }
  return make_float2(a0, a1);
}

// returns 1 if w == 0 (zw)
__device__ __noinline__ int hyp_fwd_cold(
    int l, float r2v, int zr2,
    const float* __restrict__ h1W, const float* __restrict__ h1b,
    const float* __restrict__ lns, const float* __restrict__ lnb,
    const float* __restrict__ h2W, const float* __restrict__ h2b,
    const float* __restrict__ h3W, const float* __restrict__ h3b,
    float* aL, float* xhL, float* x2L, float* wL, float* rstdL) {
  float x1[4];
#pragma unroll
  for (int q = 0; q < 4; q++) x1[q] = h1b[l + 64 * q];
  if (!zr2) {
    for (int k = 0; k < R2_DIM; k++) {
      float rk = rdlane(r2v, k);
      if (rk != 0.f) {
#pragma unroll
        for (int q = 0; q < 4; q++) x1[q] += rk * h1W[k * HID + l + 64 * q];
      }
    }
  }
  float s1 = x1[0] + x1[1] + x1[2] + x1[3];
  float s2 = x1[0] * x1[0] + x1[1] * x1[1] + x1[2] * x1[2] + x1[3] * x1[3];
  s1 = wsum_all(s1); s2 = wsum_all(s2);
  float mu = s1 * (1.f / HID);
  float var = s2 * (1.f / HID) - mu * mu;
  float rstd = rsqrtf(var + 1e-6f);
  if (l == 0) rstdL[0] = rstd;
  bool anz = false;
#pragma unroll
  for (int q = 0; q < 4; q++) {
    float xh = (x1[q] - mu) * rstd;
    xhL[l + 64 * q] = xh;
    float y = xh * lns[l + 64 * q] + lnb[l + 64 * q];
    float a = (y > 0.f) ? y : expm1f(y);
    aL[l + 64 * q] = a;
    anz |= (a != 0.f);
  }
  bool za = (__ballot(anz) == 0ull);
  float x2[4];
#pragma unroll
  for (int q = 0; q < 4; q++) x2[q] = h2b[l + 64 * q];
  if (!za) {
    for (int k4 = 0; k4 < HID / 4; k4++) {
      float4 a4 = *(const float4*)&aL[k4 * 4];
#pragma unroll
      for (int c = 0; c < 4; c++) {
        float ac = (&a4.x)[c];
        int k = k4 * 4 + c;
#pragma unroll
        for (int q = 0; q < 4; q++) x2[q] += ac * h2W[(size_t)k * HID + l + 64 * q];
      }
    }
  }
  bool x2nz = false;
#pragma unroll
  for (int q = 0; q < 4; q++) { x2L[l + 64 * q] = x2[q]; x2nz |= (x2[q] != 0.f); }
  bool zx2 = (__ballot(x2nz) == 0ull);
  int m = l & 31, kh = l >> 5;
  float p = 0.f;
  if (!zx2) {
    for (int kk = 0; kk < 128; kk++) {
      int k = kh * 128 + kk;
      p += x2L[k] * h3W[k * MIX + m];
    }
  }
  p += __shfl_xor(p, 32, 64);
  float wv = 0.f;
  if (l < 32) { wv = fmaxf(h3b[l] + p, 0.f); wL[l] = wv; }
  return (__ballot(wv != 0.f) == 0ull) ? 1 : 0;
}

// returns: .x = new r2, .y = flags bitcast (bit0 changed, bit1 zr2)
__device__ __noinline__ float2 hyp_bwd_cold(
    int l, float r2v, int zw,
    const float* __restrict__ T2,
    const float* __restrict__ h1W, const float* __restrict__ lns,
    const float* __restrict__ h2W, const float* __restrict__ h3W,
    float* cS, int* cstL, const float* rpL, const float* eL,
    const float* aL, const float* xhL, const float* wL,
    float* dx3L, float* dx2L, float* dx1L, const float* rstdL) {
  bool zd3 = true;
  if (!zw) {
    ensure_c_dev(l, T2, cS, cstL, rpL);
    int m = l & 31, ih = l >> 5;
    float p = 0.f;
    for (int ii = 0; ii < 64; ii++) {
      int i = ih * 64 + ii;
      p += eL[i] * cS[m * 129 + i];
    }
    p += __shfl_xor(p, 32, 64);
    float d3 = 0.f;
    if (l < 32) { d3 = (wL[l] > 0.f) ? (-2.f * p) : 0.f; dx3L[l] = d3; }
    zd3 = (__ballot(d3 != 0.f) == 0ull);
  }
  float g = 0.f;
  if (!zd3) {
    float rstd = rstdL[0];
    float dx2[4] = {0.f, 0.f, 0.f, 0.f};
#pragma unroll
    for (int m4 = 0; m4 < 8; m4++) {
      float4 d4 = *(const float4*)&dx3L[m4 * 4];
#pragma unroll
      for (int q = 0; q < 4; q++) {
        const float* r3 = h3W + (size_t)(l + 64 * q) * MIX + m4 * 4;
        dx2[q] += d4.x * r3[0] + d4.y * r3[1] + d4.z * r3[2] + d4.w * r3[3];
      }
    }
#pragma unroll
    for (int q = 0; q < 4; q++) dx2L[l + 64 * q] = dx2[q];
    float dxh[4];
    float s1 = 0.f, s2 = 0.f;
#pragma unroll
    for (int q = 0; q < 4; q++) {
      float da = 0.f;
      const float* row = h2W + (size_t)(l + 64 * q) * HID;
      for (int k4 = 0; k4 < HID / 4; k4++) {
        float4 w4 = *(const float4*)(row + k4 * 4);
        float4 d4 = *(const float4*)&dx2L[k4 * 4];
        da += w4.x * d4.x + w4.y * d4.y + w4.z * d4.z + w4.w * d4.w;
      }
      float a = aL[l + 64 * q];
      float dy = da * (a > 0.f ? 1.f : (a + 1.f));
      dxh[q] = dy * lns[l + 64 * q];
      s1 += dxh[q]; s2 += dxh[q] * xhL[l + 64 * q];
    }
    s1 = wsum_all(s1); s2 = wsum_all(s2);
#pragma unroll
    for (int q = 0; q < 4; q++) {
      float dx1 = rstd * (dxh[q] - s1 * (1.f / HID) - xhL[l + 64 * q] * (s2 * (1.f / HID)));
      dx1L[l + 64 * q] = dx1;
    }
    const float* row1 = h1W + (size_t)l * HID;
    for (int j4 = 0; j4 < HID / 4; j4++) {
      float4 w4 = *(const float4*)(row1 + j4 * 4);
      float4 d4 = *(const float4*)&dx1L[j4 * 4];
      g += w4.x * d4.x + w4.y * d4.y + w4.z * d4.z + w4.w * d4.w;
    }
  }
  float r2n = softt(r2v - 0.1f * g, 0.001f);
  int fl = 0;
  if (__ballot(r2n != r2v) != 0ull) fl |= 1;
  if (__ballot(r2n != 0.f) == 0ull) fl |= 2;
  return make_float2(r2n, __int_as_float(fl));
}

// ---------------- prep: G (folded), U, SX, flag, zero loss slots --------------
__global__ __launch_bounds__(256) void k_prep(const float* __restrict__ X,
                                              const float* __restrict__ decb,
                                              const float* __restrict__ decW,
                                              const float* __restrict__ h1W,
                                              const float* __restrict__ h1b,
                                              const float* __restrict__ lns,
                                              const float* __restrict__ lnb,
                                              const float* __restrict__ h2W,
                                              const float* __restrict__ h2b,
                                              const float* __restrict__ h3W,
                                              const float* __restrict__ h3b,
                                              float* __restrict__ ws,
                                              float* __restrict__ out) {
  __shared__ __align__(16) float As[8][IN_DIM];    // 16 KB
  __shared__ float Wsp[128][65];                   // 33.3 KB
  __shared__ float scr[256];
  __shared__ __align__(16) float aF[HID], xhF[HID], x2F[HID];
  __shared__ __align__(16) float wF[MIX];
  __shared__ float rsF[1];
  float* G = ws + OFF_G;
  float* U = ws + OFF_U;
  float* SX = ws + OFF_SX;
  const int tid = threadIdx.x;
  const int bx = blockIdx.x;

  if (bx == 528) {  // absorbing-state probe, wave 0 only
    if (tid < 64) {
      int z = hyp_fwd_cold(tid, 0.f, 1, h1W, h1b, lns, lnb, h2W, h2b, h3W, h3b,
                           aF, xhF, x2F, wF, rsF);
      if (tid == 0) ((int*)(ws + OFF_FLAG))[0] = z;
    }
    return;
  }
  const bool isG = (bx >= 512);

  if (bx == 0 && tid < 3) out[tid] = 0.f;          // loss accumulators (serial)
  if (bx == 0 && tid < 48) ws[OFF_LOSS + tid] = 0.f;  // loss slots (fast)

  // ---- stage A rows (X - b, or decW rows for G blocks) + SX partials ----
  {
    int g = tid >> 5;             // row 0..7
    int f0 = tid & 31;            // float4 slot base
    if (!isG) {
      int row0 = bx * 8;
      float p = 0.f;
#pragma unroll
      for (int q = 0; q < 4; q++) {
        int f4 = f0 + 32 * q;
        float4 xv = *reinterpret_cast<const float4*>(X + (size_t)(row0 + g) * IN_DIM + f4 * 4);
        float4 bv = *reinterpret_cast<const float4*>(decb + f4 * 4);
        float4 v = make_float4(xv.x - bv.x, xv.y - bv.y, xv.z - bv.z, xv.w - bv.w);
        *reinterpret_cast<float4*>(&As[g][f4 * 4]) = v;
        p += v.x * v.x + v.y * v.y + v.z * v.z + v.w * v.w;
      }
      scr[tid] = p;
    } else {
      int row0 = (bx - 512) * 8;
#pragma unroll
      for (int q = 0; q < 4; q++) {
        int f4 = f0 + 32 * q;
        float4 v = *reinterpret_cast<const float4*>(decW + (size_t)(row0 + g) * IN_DIM + f4 * 4);
        *reinterpret_cast<float4*>(&As[g][f4 * 4]) = v;
      }
    }
  }
  __syncthreads();
  if (!isG && tid < 8) {
    float s = 0.f;
#pragma unroll
    for (int q = 0; q < 32; q++) s += scr[tid * 32 + q];
    SX[bx * 8 + tid] = s;
  }

  const int j = tid & 127;        // output column
  const int gh = tid >> 7;        // row-half (4 rows each)
  float acc[4] = {0.f, 0.f, 0.f, 0.f};

  for (int kp = 0; kp < 8; kp++) {
    __syncthreads();  // WAR: previous panel's reg-cache reads done
#pragma unroll
    for (int pass = 0; pass < 8; pass++) {
      int row = pass * 16 + (tid >> 4);
      int kk = (tid & 15) * 4;
      float4 v = *reinterpret_cast<const float4*>(decW + (size_t)row * IN_DIM + kp * 64 + kk);
      Wsp[row][kk + 0] = v.x; Wsp[row][kk + 1] = v.y;
      Wsp[row][kk + 2] = v.z; Wsp[row][kk + 3] = v.w;
    }
    __syncthreads();
    float wreg[64];
#pragma unroll
    for (int kk = 0; kk < 64; kk++) wreg[kk] = Wsp[j][kk];
#pragma unroll
    for (int gi = 0; gi < 4; gi++) {
      int gg = gh * 4 + gi;      // uniform per wave -> As reads are broadcasts
      float a = acc[gi];
#pragma unroll
      for (int k4 = 0; k4 < 16; k4++) {
        float4 a4 = *reinterpret_cast<const float4*>(&As[gg][kp * 64 + k4 * 4]);
        a += a4.x * wreg[k4 * 4 + 0] + a4.y * wreg[k4 * 4 + 1] +
             a4.z * wreg[k4 * 4 + 2] + a4.w * wreg[k4 * 4 + 3];
      }
      acc[gi] = a;
    }
  }

  if (!isG) {
    int row0 = bx * 8;
#pragma unroll
    for (int gi = 0; gi < 4; gi++)
      U[(size_t)(row0 + gh * 4 + gi) * R_DIM + j] = acc[gi];
  } else {
    int row0 = (bx - 512) * 8;
#pragma unroll
    for (int gi = 0; gi < 4; gi++) {
      int rr = row0 + gh * 4 + gi;
      float gv = -0.2f * acc[gi];            // fold M = 0.8I - 0.2G
      if (rr == j) gv += 0.8f;
      G[(size_t)rr * R_DIM + j] = gv;
    }
  }
}

// ---------------- FAST path: two (b,t) per block, 2 outputs per thread -------
// R5 model: k_ista was LDS-pipe-bound (16 ds_read_b128 per thread-iter, ~12cy
// each on the shared pipe). Each thread now computes TWO output columns
// (p, p+64) from the SAME 16 r-reads, so a 256-thread block covers two (b,t)
// pairs: LDS traffic per (b,t) halves. Each lane updates only its own output
// iown = p + kh*64 (one softt + one ds_write_b32); the kh-pair partials
// combine via the validated a=b pairsum32.
__global__ __launch_bounds__(256, 2) void k_ista(float* __restrict__ ws,
                                                 float* __restrict__ out) {
  if (((const int*)(ws + OFF_FLAG))[0] == 0) return;  // cold mode: serial path
  __shared__ __align__(16) float rbuf[2][2][R_DIM];   // [bt-half][dbuf][i]
  __shared__ float scr[8];

  const int tid = threadIdx.x;
  const int half = tid >> 7;            // which bt of this block
  const int wv = tid >> 6;              // wave 0..3
  const int wbt = wv & 1;               // wave index within bt
  const int l6 = tid & 63;
  const int p = (wbt << 5) + (l6 & 31); // output pair: columns p and p+64
  const int kh = l6 >> 5;               // K-half 0/1
  const int iown = p + (kh << 6);       // this lane's owned output
  const int bt = blockIdx.x * 2 + half;
  const int b = bt >> 4;
  const int t = bt & 15;
  const float* Gg = ws + OFF_G;
  const float* Ug = ws + OFF_U;

  // Stage K-half of M columns p and p+64 (128 VGPR).
  float Ga0[64], Ga1[64];
#pragma unroll
  for (int kk = 0; kk < 64; kk++) {
    const float* row = Gg + (size_t)(kh * 64 + kk) * R_DIM;
    Ga0[kk] = row[p];
    Ga1[kk] = row[p + 64];
  }

  const float u = Ug[(size_t)bt * R_DIM + iown];
  const float u02 = 0.2f * u;

  // Both-column matvec partials from this lane's K-half; combine across the
  // kh pair; return this lane's own output's full matvec value.
  auto mvown = [&](const float* vbase) {
    const float* vp = vbase + (kh << 6);
    float s0a = 0.f, s0b = 0.f, s1a = 0.f, s1b = 0.f;
#pragma unroll
    for (int k4 = 0; k4 < 16; k4++) {
      float4 v4 = *reinterpret_cast<const float4*>(vp + k4 * 4);
      s0a += v4.x * Ga0[k4 * 4 + 0] + v4.y * Ga0[k4 * 4 + 1];
      s0b += v4.z * Ga0[k4 * 4 + 2] + v4.w * Ga0[k4 * 4 + 3];
      s1a += v4.x * Ga1[k4 * 4 + 0] + v4.y * Ga1[k4 * 4 + 1];
      s1b += v4.z * Ga1[k4 * 4 + 2] + v4.w * Ga1[k4 * 4 + 3];
    }
    float mv0 = pairsum32(s0a + s0b);   // full matvec for column p
    float mv1 = pairsum32(s1a + s1b);   // full matvec for column p+64
    return kh ? mv1 : mv0;
  };

  // it = 0: r_prev = warm = 0 -> r = softt(0.2*u)
  float r = softt(u02, 0.001f);
  rbuf[half][1][iown] = r;
  __syncthreads();
#pragma unroll 1
  for (int it = 1; it < MAX_IT; it++) {
    float mv = mvown(&rbuf[half][it & 1][0]);
    r = softt(mv + u02, 0.001f);
    rbuf[half][(it & 1) ^ 1][iown] = r;   // write buffer != read buffer
    __syncthreads();
  }
  // last write (it=11) went to rbuf[half][0]; barrier done.
  float mvf = mvown(&rbuf[half][0][0]);
  float gb = 0.8f * r - mvf;              // = 0.2*(G r)_iown
  float l1 = r * (5.f * gb) - 2.f * r * u;
  float l2 = r * r;
  l1 = wsum(l1); l2 = wsum(l2);
  if (l6 == 0) { scr[wv * 2 + 0] = l1; scr[wv * 2 + 1] = l2; }
  __syncthreads();
  if ((tid & 127) == 0) {                 // one thread per bt-half
    float s1 = scr[half * 4 + 0] + scr[half * 4 + 2];
    float s2 = scr[half * 4 + 1] + scr[half * 4 + 3];
    float sx = ws[OFF_SX + bt];
    float* loss = ws + OFF_LOSS;
    atomicAdd(&loss[0 * 16 + t], sx);     // spat_rhat: decode(0) vs x
    atomicAdd(&loss[1 * 16 + t], s1 + sx);// spat_rbar
    atomicAdd(&loss[2 * 16 + t], s2);     // temp loss: ||r - 0||^2
  }
  if (t == T_SZ - 1) out[3 + b * R_DIM + iown] = r;
  if (t == 0 && wbt == 0) out[3 + B_SZ * R_DIM + b * R2_DIM + l6] = 0.f;
}

__global__ void k_fin(const float* __restrict__ ws, float* __restrict__ out) {
  if (((const int*)(ws + OFF_FLAG))[0] == 0) return;
  int k = threadIdx.x;
  if (k < 3) {
    float s = 0.f;
#pragma unroll
    for (int t = 0; t < 16; t++) s += ws[OFF_LOSS + k * 16 + t];
    out[k] = s * (1.f / (B_SZ * T_SZ));
  }
}

// ---------------- SERIAL fallback: bit-faithful R0 body (proven green) -------
__global__ __launch_bounds__(256, 1) void k_main(
    float* __restrict__ ws, const float* __restrict__ T2,
    const float* __restrict__ h1W, const float* __restrict__ h1b,
    const float* __restrict__ lns, const float* __restrict__ lnb,
    const float* __restrict__ h2W, const float* __restrict__ h2b,
    const float* __restrict__ h3W, const float* __restrict__ h3b,
    float* __restrict__ out) {
  if (((const int*)(ws + OFF_FLAG))[0] != 0) return;  // fast path covers
  __shared__ __align__(16) float rbuf[2][R_DIM];
  __shared__ __align__(16) float rhL[R_DIM];
  __shared__ __align__(16) float cS[MIX * 129];
  __shared__ __align__(16) float aL[HID];
  __shared__ __align__(16) float xhL[HID];
  __shared__ __align__(16) float x2L[HID];
  __shared__ __align__(16) float dx1L[HID];
  __shared__ __align__(16) float dx2L[HID];
  __shared__ __align__(16) float wL[MIX];
  __shared__ __align__(16) float dx3L[MIX];
  __shared__ __align__(16) float eL[R_DIM];
  __shared__ __align__(16) float rpL[R_DIM];
  __shared__ float rstdL[1];
  __shared__ int cstL[1];
  __shared__ int flagL[1];

  const int tid = threadIdx.x;
  const int w = tid >> 6;
  const int l6 = tid & 63;
  const int i = (w << 5) + (l6 & 31);
  const int kh = l6 >> 5;
  const int b = blockIdx.x;
  const float* Gg = ws + OFF_G;
  const float* Ug = ws + OFF_U;
  const float* SXg = ws + OFF_SX;

  float r2v = 0.f;
  bool zr2 = true, rhv;

  if (w == 0) {
    int z = hyp_fwd_cold(l6, 0.f, 1, h1W, h1b, lns, lnb, h2W, h2b, h3W, h3b,
                         aL, xhL, x2L, wL, rstdL);
    if (l6 == 0) flagL[0] = z;
  }
  __syncthreads();
  bool zw = flagL[0] != 0;

  float Ga[64];
#pragma unroll
  for (int kk = 0; kk < 64; kk++)
    Ga[kk] = Gg[(size_t)(kh * 64 + kk) * R_DIM + i];

  float rOwn = 0.f;
  float lc0 = 0.f, lc1 = 0.f, lc2 = 0.f, sxa = 0.f;

  auto mvhalf = [&](const float* vptr) {
    const float* vp = vptr + (kh << 6);
    float p0 = 0.f, p1 = 0.f, p2 = 0.f, p3 = 0.f;
#pragma unroll
    for (int k4 = 0; k4 < 16; k4++) {
      float4 v4 = *reinterpret_cast<const float4*>(vp + k4 * 4);
      p0 += v4.x * Ga[k4 * 4 + 0];
      p1 += v4.y * Ga[k4 * 4 + 1];
      p2 += v4.z * Ga[k4 * 4 + 2];
      p3 += v4.w * Ga[k4 * 4 + 3];
    }
    float pm = (p0 + p1) + (p2 + p3);
    return pm + __shfl_xor(pm, 32, 64);
  };

  float rh_own = 0.f;
  auto refresh_rh = [&]() {
    if (zw) { rh_own = 0.f; return; }
    __syncthreads();
    if (w == 0) {
      float2 rr = rhat_cold(l6, T2, cS, cstL, rpL, wL);
      rhL[l6] = rr.x; rhL[64 + l6] = rr.y;
    }
    __syncthreads();
    rh_own = rhL[i];
  };

  float un = Ug[(size_t)(b * T_SZ) * R_DIM + i];
  float sxn = SXg[b * T_SZ];

#pragma unroll 1
  for (int t = 0; t < T_SZ; t++) {
    float u = un, sxv = sxn;
    if (t < T_SZ - 1) {
      un = Ug[(size_t)(b * T_SZ + t + 1) * R_DIM + i];
      sxn = SXg[b * T_SZ + t + 1];
    }
    float u02 = 0.2f * u;
    if (kh == 0) rpL[i] = rOwn;
    if (tid == 0) cstL[0] = 0;
    refresh_rh();
    rhv = true;
    rOwn = rh_own;
    __syncthreads();
    if (kh == 0) rbuf[0][i] = rOwn;
    __syncthreads();
    bool rzero = zw;
#pragma unroll 1
    for (int it = 0; it < MAX_IT; it++) {
      if (!rhv) { refresh_rh(); rhv = true; }
      float mv = 0.f;
      if (!rzero) mv = mvhalf(rbuf[it & 1]);
      rzero = false;
      float rNew = softt(mv + 0.2f * rh_own + u02, 0.001f);
      if (kh == 0) {
        eL[i] = rOwn - rh_own;
        rbuf[(it & 1) ^ 1][i] = rNew;
      }
      rOwn = rNew;
      __syncthreads();
      if (!(zw && zr2)) {
        if (w == 0) {
          float2 br = hyp_bwd_cold(l6, r2v, zw ? 1 : 0, T2, h1W, lns, h2W, h3W,
                                   cS, cstL, rpL, eL, aL, xhL, wL,
                                   dx3L, dx2L, dx1L, rstdL);
          r2v = br.x;
          if (l6 == 0) flagL[0] = __float_as_int(br.y);
        }
        __syncthreads();
        int fl = flagL[0];
        zr2 = (fl & 2) != 0;
        if (fl & 1) {
          if (w == 0) {
            int z = hyp_fwd_cold(l6, r2v, zr2 ? 1 : 0, h1W, h1b, lns, lnb,
                                 h2W, h2b, h3W, h3b, aL, xhL, x2L, wL, rstdL);
            if (l6 == 0) flagL[0] = z;
          }
          __syncthreads();
          zw = flagL[0] != 0;
          rhv = false;
        }
      }
    }
    if (!rhv) { refresh_rh(); rhv = true; }
    {
      float mv = mvhalf(rbuf[MAX_IT & 1]);
      float gb = 0.8f * rOwn - mv;
      if (kh == 0) lc1 += rOwn * (5.f * gb) - 2.f * rOwn * u;
      if (zw) {
        if (kh == 0) lc2 += rOwn * rOwn;
      } else {
        float mvh = mvhalf(rhL);
        float gh = 0.8f * rh_own - mvh;
        if (kh == 0) {
          lc0 += rh_own * (5.f * gh) - 2.f * rh_own * u;
          float d = rOwn - rh_own;
          lc2 += d * d;
        }
      }
      if (tid == 0) sxa += sxv;
    }
  }

  const float inv = 1.f / (B_SZ * T_SZ);
  float t0 = wsum(lc0), t1 = wsum(lc1), t2 = wsum(lc2);
  if (l6 == 0) {
    float s = (w == 0) ? sxa : 0.f;
    atomicAdd(&out[0], (t0 + s) * inv);
    atomicAdd(&out[1], (t1 + s) * inv);
    atomicAdd(&out[2], t2 * inv);
  }
  if (kh == 0) out[3 + b * R_DIM + i] = rOwn;
  if (w == 0) out[3 + B_SZ * R_DIM + b * R2_DIM + l6] = r2v;
}

extern "C" void kernel_launch(void* const* d_in, const int* in_sizes, int n_in,
                              void* d_out, int out_size, void* d_ws, size_t ws_size,
                              hipStream_t stream) {
  const float* X = (const float*)d_in[0];
  const float* decW = (const float*)d_in[1];
  const float* decb = (const float*)d_in[2];
  const float* temporal = (const float*)d_in[3];
  const float* h1W = (const float*)d_in[4];
  const float* h1b = (const float*)d_in[5];
  const float* lns = (const float*)d_in[6];
  const float* lnb = (const float*)d_in[7];
  const float* h2W = (const float*)d_in[8];
  const float* h2b = (const float*)d_in[9];
  const float* h3W = (const float*)d_in[10];
  const float* h3b = (const float*)d_in[11];
  float* ws = (float*)d_ws;  // ~2.22 MiB used
  float* out = (float*)d_out;

  k_prep<<<529, 256, 0, stream>>>(X, decb, decW, h1W, h1b, lns, lnb,
                                  h2W, h2b, h3W, h3b, ws, out);
  k_main<<<B_SZ, 256, 0, stream>>>(ws, temporal, h1W, h1b, lns, lnb,
                                   h2W, h2b, h3W, h3b, out);
  k_ista<<<B_SZ * T_SZ / 2, 256, 0, stream>>>(ws, out);
  k_fin<<<1, 64, 0, stream>>>(ws, out);
}